// Round 9
// baseline (978.090 us; speedup 1.0000x reference)
//
#include <hip/hip_runtime.h>
#include <hip/hip_cooperative_groups.h>

namespace cg = cooperative_groups;

#define N_PTS 300000
#define NPAD  300032   // multiple of 256
#define ZROW  N_PTS    // zeroed feature row used for missing neighbors

typedef _Float16 f16;
typedef _Float16 f16x8 __attribute__((ext_vector_type(8)));
typedef float    f32x4 __attribute__((ext_vector_type(4)));

__device__ __forceinline__ f16 f2h(float x) { return (f16)x; }

union u4f16 { uint4 u; f16x8 h; };

// Fragment-linear weight layouts (so MFMA B-operands are lane-consecutive):
//   Wt1 / Wt3 : idx = (((k*2+ks)*4+nt)*64 + lane)*8 + j
//               value = W[k][d=ks*32+q*8+j][c=nt*16+ln]   (q=lane>>4, ln=lane&15)
//   Wt2b      : idx = ((k*4+nt)*64 + lane)*8 + j
//               value = W2b[k][d=q*8+j][c=nt*16+ln]

struct Params {
    const float *feat, *W2a, *s2a, *b2a, *W1, *W2b, *W3;
    const float *A1w, *A1b, *A2w, *A2b, *Wf, *sf, *bf;
    const float *bn1_s, *bn1_b, *bn2b_s, *bn2b_b, *bn3_s, *bn3_b;
    const int *nbr1, *nbr2;
    f16 *featf, *hf, *msf, *Wt1, *Wt2b, *Wt3;
    float *pooled, *out;
};

// ---------------------------------------------------------------------------
// phase 1 helpers: weight repack + pooled init (grid-stride) and per-wave
// feature-prep + bottleneck unit (64 rows).
// ---------------------------------------------------------------------------
__device__ __forceinline__ void repack_elem(const Params& P, int i)
{
    if (i < 36864) {                       // Wt1
        int j = i & 7, lane = (i >> 3) & 63, nt = (i >> 9) & 3,
            ks = (i >> 11) & 1, k = i >> 12;
        int d = ks * 32 + (lane >> 4) * 8 + j, c = nt * 16 + (lane & 15);
        P.Wt1[i] = f2h(P.W1[(k << 12) + (d << 6) + c]);
    } else if (i < 73728) {                // Wt3
        int ii = i - 36864;
        int j = ii & 7, lane = (ii >> 3) & 63, nt = (ii >> 9) & 3,
            ks = (ii >> 11) & 1, k = ii >> 12;
        int d = ks * 32 + (lane >> 4) * 8 + j, c = nt * 16 + (lane & 15);
        P.Wt3[ii] = f2h(P.W3[(k << 12) + (d << 6) + c]);
    } else if (i < 92160) {                // Wt2b
        int ii = i - 73728;
        int j = ii & 7, lane = (ii >> 3) & 63, nt = (ii >> 9) & 3, k = ii >> 11;
        int d = (lane >> 4) * 8 + j, c = nt * 16 + (lane & 15);
        P.Wt2b[ii] = f2h(P.W2b[k * 2048 + (d << 6) + c]);
    } else if (i < 92352) {                // pooled zero-init
        P.pooled[i - 92160] = 0.f;
    }
}

__device__ __forceinline__ void head_unit(const Params& P, int u, int lane)
{
    int n0 = u * 64;
    int ln = lane & 15, q = lane >> 4;

    f16x8 a[4][2];
#pragma unroll
    for (int mt = 0; mt < 4; mt++) {
        int n = n0 + mt * 16 + ln;
#pragma unroll
        for (int ks = 0; ks < 2; ks++) {
            u4f16 v;
            if (n < N_PTS) {
                const float* p = P.feat + (long)n * 64 + ks * 32 + q * 8;
                float4 lo = *(const float4*)p;
                float4 hi = *(const float4*)(p + 4);
                v.h[0] = f2h(lo.x); v.h[1] = f2h(lo.y);
                v.h[2] = f2h(lo.z); v.h[3] = f2h(lo.w);
                v.h[4] = f2h(hi.x); v.h[5] = f2h(hi.y);
                v.h[6] = f2h(hi.z); v.h[7] = f2h(hi.w);
            } else {
                v.u = make_uint4(0u, 0u, 0u, 0u);
            }
            a[mt][ks] = v.h;
            *(uint4*)(P.featf + (long)n * 64 + ks * 32 + q * 8) = v.u;
        }
    }

    f32x4 acc[4][2];
    for (int mt = 0; mt < 4; mt++) for (int nt = 0; nt < 2; nt++)
        acc[mt][nt] = (f32x4){0.f, 0.f, 0.f, 0.f};
#pragma unroll
    for (int ks = 0; ks < 2; ks++)
#pragma unroll
        for (int nt = 0; nt < 2; nt++) {
            f16x8 b;
#pragma unroll
            for (int j = 0; j < 8; j++)
                b[j] = f2h(P.W2a[(ks * 32 + q * 8 + j) * 32 + nt * 16 + ln]);
#pragma unroll
            for (int mt = 0; mt < 4; mt++)
                acc[mt][nt] = __builtin_amdgcn_mfma_f32_16x16x32_f16(a[mt][ks], b, acc[mt][nt], 0, 0, 0);
        }

#pragma unroll
    for (int nt = 0; nt < 2; nt++) {
        int ch = nt * 16 + ln;
        float s = P.s2a[ch], bb = P.b2a[ch];
#pragma unroll
        for (int mt = 0; mt < 4; mt++)
#pragma unroll
            for (int r = 0; r < 4; r++) {
                int n = n0 + mt * 16 + q * 4 + r;
                float v = (n < N_PTS) ? fmaxf(acc[mt][nt][r] * s + bb, 0.f) : 0.f;
                P.hf[(long)n * 32 + ch] = f2h(v);
            }
    }
}

// ---------------------------------------------------------------------------
// phase 2: sparse-conv (identical inner loop to the verified 174 µs kernel)
// ---------------------------------------------------------------------------
template <int CIN>
__device__ __forceinline__ void loadrows(
    uint4 (&dst)[4][CIN / 32], const int (&idx)[4],
    const f16* __restrict__ src, int q)
{
#pragma unroll
    for (int mt = 0; mt < 4; mt++) {
        const f16* p = src + (long)idx[mt] * CIN + q * 8;
#pragma unroll
        for (int ks = 0; ks < CIN / 32; ks++)
            dst[mt][ks] = *(const uint4*)(p + ks * 32);
    }
}

__device__ __forceinline__ void loadidx(
    int (&dst)[4], const int* __restrict__ nbr, int k, int n0, int ln)
{
    const int* nb = nbr + k * N_PTS;
#pragma unroll
    for (int mt = 0; mt < 4; mt++) {
        int nn = n0 + mt * 16 + ln;
        int v = (nn < N_PTS) ? nb[nn] : -1;
        dst[mt] = (v < 0) ? ZROW : v;
    }
}

template <int CIN>
__device__ __forceinline__ void conv_path(
    const f16* __restrict__ src, const f16* WtL,   // WtL points into LDS
    const int* __restrict__ nbr,
    int lane, int n0,
    const float* __restrict__ bns, const float* __restrict__ bnb,
    f16* __restrict__ msf, int colBase, float* __restrict__ pooled)
{
    constexpr int KS = CIN / 32;
    int ln = lane & 15, q = lane >> 4;

    f32x4 acc[4][4];
    for (int mt = 0; mt < 4; mt++) for (int nt = 0; nt < 4; nt++)
        acc[mt][nt] = (f32x4){0.f, 0.f, 0.f, 0.f};

    int  idxr[4][4];      // idx ring, distance 4
    uint4 raw[4][4][KS];  // row ring, depth 3

#pragma unroll
    for (int k = 0; k < 4; k++) loadidx(idxr[k], nbr, k, n0, ln);
#pragma unroll
    for (int k = 0; k < 3; k++) loadrows<CIN>(raw[k], idxr[k], src, q);
    __builtin_amdgcn_sched_barrier(0);

#pragma unroll
    for (int k = 0; k < 9; k++) {
        if (k + 3 < 9) loadrows<CIN>(raw[(k + 3) & 3], idxr[(k + 3) & 3], src, q);
        if (k + 4 < 9) loadidx(idxr[k & 3], nbr, k + 4, n0, ln);  // slot (k+4)&3 == k&3
        __builtin_amdgcn_sched_barrier(0);   // loads must be ISSUED before MFMAs
        const f16* Wk = WtL + k * (KS * 4 * 512);
        __builtin_amdgcn_s_setprio(1);
#pragma unroll
        for (int ks = 0; ks < KS; ks++)
#pragma unroll
            for (int nt = 0; nt < 4; nt++) {
                f16x8 b = *(const f16x8*)(Wk + (ks * 4 + nt) * 512 + lane * 8);
#pragma unroll
                for (int mt = 0; mt < 4; mt++) {
                    u4f16 v; v.u = raw[k & 3][mt][ks];
                    acc[mt][nt] = __builtin_amdgcn_mfma_f32_16x16x32_f16(v.h, b, acc[mt][nt], 0, 0, 0);
                }
            }
        __builtin_amdgcn_s_setprio(0);
    }

    // epilogue: BN + ReLU, store ms fp16, channel max -> pooled
#pragma unroll
    for (int nt = 0; nt < 4; nt++) {
        int ch = colBase + nt * 16 + ln;
        float s = bns[nt * 16 + ln], bb = bnb[nt * 16 + ln];
        float cmax = 0.f;
#pragma unroll
        for (int mt = 0; mt < 4; mt++)
#pragma unroll
            for (int r = 0; r < 4; r++) {
                int n = n0 + mt * 16 + q * 4 + r;   // always < NPAD
                float v = fmaxf(acc[mt][nt][r] * s + bb, 0.f);
                msf[(long)n * 192 + ch] = f2h(v);
                if (n < N_PTS) cmax = fmaxf(cmax, v);
            }
        cmax = fmaxf(cmax, __shfl_xor(cmax, 16));
        cmax = fmaxf(cmax, __shfl_xor(cmax, 32));
        if (q == 0) atomicMax((int*)(pooled + ch), __float_as_int(cmax));
    }
}

// ---------------------------------------------------------------------------
// phase 3: fusion unit (256 pts per block-unit; 8 waves x 32 pts)
// ---------------------------------------------------------------------------
__device__ __forceinline__ void fuse_unit(
    const Params& P, const f16* sWf, int g, int wave, int lane)
{
    int n0 = g * 256 + wave * 32;
    int ln = lane & 15, q = lane >> 4;

    uint4 araw[6][2];
#pragma unroll
    for (int kt = 0; kt < 6; kt++)
#pragma unroll
        for (int mt = 0; mt < 2; mt++)
            araw[kt][mt] = *(const uint4*)(P.msf + (long)(n0 + mt * 16 + ln) * 192 + kt * 32 + q * 8);

    f32x4 acc[2][4];
    for (int mt = 0; mt < 2; mt++) for (int nt = 0; nt < 4; nt++)
        acc[mt][nt] = (f32x4){0.f, 0.f, 0.f, 0.f};

#pragma unroll
    for (int kt = 0; kt < 6; kt++)
#pragma unroll
        for (int nt = 0; nt < 4; nt++) {
            f16x8 b = *(const f16x8*)(sWf + ((kt * 4 + nt) * 64 + lane) * 8);
#pragma unroll
            for (int mt = 0; mt < 2; mt++) {
                u4f16 v; v.u = araw[kt][mt];
                acc[mt][nt] = __builtin_amdgcn_mfma_f32_16x16x32_f16(v.h, b, acc[mt][nt], 0, 0, 0);
            }
        }

#pragma unroll
    for (int nt = 0; nt < 4; nt++) {
        int ch = nt * 16 + ln;
        float s = P.sf[ch], bb = P.bf[ch];
#pragma unroll
        for (int mt = 0; mt < 2; mt++)
#pragma unroll
            for (int r = 0; r < 4; r++) {
                int n = n0 + mt * 16 + q * 4 + r;
                if (n < N_PTS)
                    __builtin_nontemporal_store(fmaxf(acc[mt][nt][r] * s + bb, 0.f),
                                                &P.out[(long)n * 64 + ch]);
            }
    }
}

// ---------------------------------------------------------------------------
// mega kernel: head -> grid.sync -> conv -> grid.sync -> fuse.
// phases: 7 = all (cooperative); 1/2/4 = single phase (fallback launches).
// ---------------------------------------------------------------------------
__global__ __launch_bounds__(512, 4) void k_mega(Params P, int phases)
{
    __shared__ __align__(16) char smemraw[9 * 64 * 64 * 2];   // 73728 B

    int tid = threadIdx.x, lane = tid & 63, wave = tid >> 6;
    int G = gridDim.x;

    if (phases & 1) {
        for (int i = blockIdx.x * 512 + tid; i < 92352; i += G * 512)
            repack_elem(P, i);
        for (int u = blockIdx.x * 8 + wave; u < 4688; u += G * 8)
            head_unit(P, u, lane);
    }
    if (phases == 7) { __threadfence(); cg::this_grid().sync(); }

    if (phases & 2) {
        int path = blockIdx.x % 3, b3 = blockIdx.x / 3, NB3 = G / 3;
        f16* smem = (f16*)smemraw;
        const f16* Wsrc = (path == 0) ? P.Wt1 : (path == 1) ? P.Wt2b : P.Wt3;
        int nchunk = (path == 1) ? (9 * 32 * 64 / 8) : (9 * 64 * 64 / 8);
        for (int i = tid; i < nchunk; i += 512)
            ((uint4*)smemraw)[i] = ((const uint4*)Wsrc)[i];
        __syncthreads();
        for (int g = b3; g < 586; g += NB3) {
            int n0 = (g * 8 + wave) * 64;
            if (path == 0)
                conv_path<64>(P.featf, smem, P.nbr1, lane, n0, P.bn1_s,  P.bn1_b,  P.msf, 0,   P.pooled);
            else if (path == 1)
                conv_path<32>(P.hf,    smem, P.nbr1, lane, n0, P.bn2b_s, P.bn2b_b, P.msf, 64,  P.pooled);
            else
                conv_path<64>(P.featf, smem, P.nbr2, lane, n0, P.bn3_s,  P.bn3_b,  P.msf, 128, P.pooled);
        }
    }
    if (phases == 7) { __threadfence(); cg::this_grid().sync(); }

    if (phases & 4) {
        float* sp    = (float*)smemraw;            // 768 B
        float* sa1   = (float*)(smemraw + 768);    // 64 B
        float* sattn = (float*)(smemraw + 832);    // 768 B
        f16*   sWf   = (f16*)(smemraw + 1600);     // 24576 B
        __syncthreads();
        if (tid < 192) sp[tid] = P.pooled[tid];
        __syncthreads();
        if (tid < 16) {
            float a = P.A1b[tid];
            for (int i = 0; i < 192; i++) a += sp[i] * P.A1w[i * 16 + tid];
            sa1[tid] = fmaxf(a, 0.f);
        }
        __syncthreads();
        if (tid < 192) {
            float a = P.A2b[tid];
            for (int i = 0; i < 16; i++) a += sa1[i] * P.A2w[i * 192 + tid];
            sattn[tid] = 1.f / (1.f + expf(-a));
        }
        __syncthreads();
        for (int i = tid; i < 12288; i += 512) {   // 6*4*64*8 fragment-linear
            int j = i & 7, ll = (i >> 3) & 63, nt = (i >> 9) & 3, kt = i >> 11;
            int jrow = kt * 32 + (ll >> 4) * 8 + j, c = nt * 16 + (ll & 15);
            sWf[i] = f2h(P.Wf[jrow * 64 + c] * sattn[jrow]);
        }
        __syncthreads();
        for (int g = blockIdx.x; g < 1172; g += G)
            fuse_unit(P, sWf, g, wave, lane);
    }
}

// ---------------------------------------------------------------------------
extern "C" void kernel_launch(void* const* d_in, const int* in_sizes, int n_in,
                              void* d_out, int out_size, void* d_ws, size_t ws_size,
                              hipStream_t stream)
{
    char* ws = (char*)d_ws;
    size_t off = 0;
    f16* featf = (f16*)(ws + off); off += (size_t)NPAD * 64 * 2;
    f16* hf    = (f16*)(ws + off); off += (size_t)NPAD * 32 * 2;
    f16* msf   = (f16*)(ws + off); off += (size_t)NPAD * 192 * 2;
    f16* Wt1   = (f16*)(ws + off); off += 9 * 64 * 64 * 2;
    f16* Wt3   = (f16*)(ws + off); off += 9 * 64 * 64 * 2;
    f16* Wt2b  = (f16*)(ws + off); off += 9 * 32 * 64 * 2;
    float* pooled = (float*)(ws + off); off += 256 * 4;

    Params P;
    P.feat   = (const float*)d_in[0];
    P.W1     = (const float*)d_in[1];
    P.bn1_s  = (const float*)d_in[2];
    P.bn1_b  = (const float*)d_in[3];
    P.W2a    = (const float*)d_in[4];
    P.s2a    = (const float*)d_in[5];
    P.b2a    = (const float*)d_in[6];
    P.W2b    = (const float*)d_in[7];
    P.bn2b_s = (const float*)d_in[8];
    P.bn2b_b = (const float*)d_in[9];
    P.W3     = (const float*)d_in[10];
    P.bn3_s  = (const float*)d_in[11];
    P.bn3_b  = (const float*)d_in[12];
    P.A1w    = (const float*)d_in[13];
    P.A1b    = (const float*)d_in[14];
    P.A2w    = (const float*)d_in[15];
    P.A2b    = (const float*)d_in[16];
    P.Wf     = (const float*)d_in[17];
    P.sf     = (const float*)d_in[18];
    P.bf     = (const float*)d_in[19];
    P.nbr1   = (const int*)d_in[20];
    P.nbr2   = (const int*)d_in[21];
    P.featf = featf; P.hf = hf; P.msf = msf;
    P.Wt1 = Wt1; P.Wt2b = Wt2b; P.Wt3 = Wt3;
    P.pooled = pooled; P.out = (float*)d_out;

    static int s_init = 0, s_coop = 0, s_G = 255;
    if (!s_init) {
        int coop = 0, ncu = 0, occ = 0;
        if (hipDeviceGetAttribute(&coop, hipDeviceAttributeCooperativeLaunch, 0) != hipSuccess) coop = 0;
        if (hipDeviceGetAttribute(&ncu, hipDeviceAttributeMultiprocessorCount, 0) != hipSuccess || ncu <= 0) ncu = 256;
        if (hipOccupancyMaxActiveBlocksPerMultiprocessor(
                &occ, reinterpret_cast<const void*>(k_mega), 512, 0) != hipSuccess || occ <= 0) occ = 1;
        s_coop = coop;
        s_G = (occ * ncu / 3) * 3;
        if (s_G < 3) s_G = 3;
        s_init = 1;
    }

    if (s_coop) {
        int phases = 7;
        void* args[] = { (void*)&P, (void*)&phases };
        if (hipLaunchCooperativeKernel(reinterpret_cast<const void*>(k_mega),
                                       dim3(s_G), dim3(512), args, 0u, stream) != hipSuccess) {
            s_coop = 0;   // cooperative rejected: fall through to phase launches
            k_mega<<<s_G, 512, 0, stream>>>(P, 1);
            k_mega<<<s_G, 512, 0, stream>>>(P, 2);
            k_mega<<<s_G, 512, 0, stream>>>(P, 4);
        }
    } else {
        k_mega<<<s_G, 512, 0, stream>>>(P, 1);
        k_mega<<<s_G, 512, 0, stream>>>(P, 2);
        k_mega<<<s_G, 512, 0, stream>>>(P, 4);
    }
}

// Round 11
// 438.712 us; speedup vs baseline: 2.2295x; 2.2295x over previous
//
#include <hip/hip_runtime.h>

#define N_PTS 300000
#define NPAD  300032   // multiple of 256
#define ZROW  N_PTS    // zeroed feature row used for missing neighbors

typedef _Float16 f16;
typedef _Float16 f16x8 __attribute__((ext_vector_type(8)));
typedef float    f32x4 __attribute__((ext_vector_type(4)));

__device__ __forceinline__ f16 f2h(float x) { return (f16)x; }

union u4f16 { uint4 u; f16x8 h; };

#define HEAD_BLOCKS (NPAD / 256)   // 1172
#define WP_BLOCKS   361            // 361*256 covers 92160 weights + 192 pooled-init

// Fragment-linear weight layouts (so MFMA B-operands are lane-consecutive):
//   Wt1 / Wt3 : idx = (((k*2+ks)*4+nt)*64 + lane)*8 + j
//               value = W[k][d=ks*32+q*8+j][c=nt*16+ln]   (q=lane>>4, ln=lane&15)
//   Wt2b      : idx = ((k*4+nt)*64 + lane)*8 + j
//               value = W2b[k][d=q*8+j][c=nt*16+ln]

// ---------------------------------------------------------------------------
// head: fused feature-prep + bottleneck + weight repack + pooled zero-init.
// ---------------------------------------------------------------------------
__global__ __launch_bounds__(256) void k_head(
    const float* __restrict__ feat, const float* __restrict__ W2a,
    const float* __restrict__ s2a, const float* __restrict__ b2a,
    const float* __restrict__ W1, const float* __restrict__ W2b,
    const float* __restrict__ W3,
    f16* __restrict__ featf, f16* __restrict__ hf,
    f16* __restrict__ Wt1, f16* __restrict__ Wt2b, f16* __restrict__ Wt3,
    float* __restrict__ pooled)
{
    if (blockIdx.x >= HEAD_BLOCKS) {   // weight-repack blocks
        int i = (blockIdx.x - HEAD_BLOCKS) * 256 + threadIdx.x;
        if (i < 36864) {                       // Wt1
            int j = i & 7, lane = (i >> 3) & 63, nt = (i >> 9) & 3,
                ks = (i >> 11) & 1, k = i >> 12;
            int d = ks * 32 + (lane >> 4) * 8 + j, c = nt * 16 + (lane & 15);
            Wt1[i] = f2h(W1[(k << 12) + (d << 6) + c]);
        } else if (i < 73728) {                // Wt3
            int ii = i - 36864;
            int j = ii & 7, lane = (ii >> 3) & 63, nt = (ii >> 9) & 3,
                ks = (ii >> 11) & 1, k = ii >> 12;
            int d = ks * 32 + (lane >> 4) * 8 + j, c = nt * 16 + (lane & 15);
            Wt3[ii] = f2h(W3[(k << 12) + (d << 6) + c]);
        } else if (i < 92160) {                // Wt2b
            int ii = i - 73728;
            int j = ii & 7, lane = (ii >> 3) & 63, nt = (ii >> 9) & 3, k = ii >> 11;
            int d = (lane >> 4) * 8 + j, c = nt * 16 + (lane & 15);
            Wt2b[ii] = f2h(W2b[k * 2048 + (d << 6) + c]);
        } else if (i < 92352) {                // pooled zero-init (replaces memset)
            pooled[i - 92160] = 0.f;
        }
        return;
    }

    int lane = threadIdx.x & 63, wave = threadIdx.x >> 6;
    int n0 = (blockIdx.x * 4 + wave) * 64;
    int ln = lane & 15, q = lane >> 4;

    f16x8 a[4][2];
#pragma unroll
    for (int mt = 0; mt < 4; mt++) {
        int n = n0 + mt * 16 + ln;
#pragma unroll
        for (int ks = 0; ks < 2; ks++) {
            u4f16 v;
            if (n < N_PTS) {
                const float* p = feat + (long)n * 64 + ks * 32 + q * 8;
                float4 lo = *(const float4*)p;
                float4 hi = *(const float4*)(p + 4);
                v.h[0] = f2h(lo.x); v.h[1] = f2h(lo.y);
                v.h[2] = f2h(lo.z); v.h[3] = f2h(lo.w);
                v.h[4] = f2h(hi.x); v.h[5] = f2h(hi.y);
                v.h[6] = f2h(hi.z); v.h[7] = f2h(hi.w);
            } else {
                v.u = make_uint4(0u, 0u, 0u, 0u);
            }
            a[mt][ks] = v.h;
            *(uint4*)(featf + (long)n * 64 + ks * 32 + q * 8) = v.u;
        }
    }

    // B = W2a^T fragments converted inline from fp32 (8 KB, L1-resident)
    f32x4 acc[4][2];
    for (int mt = 0; mt < 4; mt++) for (int nt = 0; nt < 2; nt++)
        acc[mt][nt] = (f32x4){0.f, 0.f, 0.f, 0.f};
#pragma unroll
    for (int ks = 0; ks < 2; ks++)
#pragma unroll
        for (int nt = 0; nt < 2; nt++) {
            f16x8 b;
#pragma unroll
            for (int j = 0; j < 8; j++)
                b[j] = f2h(W2a[(ks * 32 + q * 8 + j) * 32 + nt * 16 + ln]);
#pragma unroll
            for (int mt = 0; mt < 4; mt++)
                acc[mt][nt] = __builtin_amdgcn_mfma_f32_16x16x32_f16(a[mt][ks], b, acc[mt][nt], 0, 0, 0);
        }

#pragma unroll
    for (int nt = 0; nt < 2; nt++) {
        int ch = nt * 16 + ln;
        float s = s2a[ch], bb = b2a[ch];
#pragma unroll
        for (int mt = 0; mt < 4; mt++)
#pragma unroll
            for (int r = 0; r < 4; r++) {
                int n = n0 + mt * 16 + q * 4 + r;
                float v = (n < N_PTS) ? fmaxf(acc[mt][nt][r] * s + bb, 0.f) : 0.f;
                hf[(long)n * 32 + ch] = f2h(v);
            }
    }
}

// ---------------------------------------------------------------------------
// sparse-conv path: 64 pts/wave, rotating gather ring, ZROW remap.
// B operands come from LDS (fragment-linear) so they never touch vmcnt.
// 8 waves per block share one staged weight set (72 KB -> 2 blocks/CU).
// Paths interleaved per block (blockIdx%3). Launched as TWO tile-range
// halves (g0 offset) so k_head/k_fuse can surface in rocprof top-5.
// ---------------------------------------------------------------------------
template <int CIN>
__device__ __forceinline__ void loadrows(
    uint4 (&dst)[4][CIN / 32], const int (&idx)[4],
    const f16* __restrict__ src, int q)
{
#pragma unroll
    for (int mt = 0; mt < 4; mt++) {
        const f16* p = src + (long)idx[mt] * CIN + q * 8;
#pragma unroll
        for (int ks = 0; ks < CIN / 32; ks++)
            dst[mt][ks] = *(const uint4*)(p + ks * 32);
    }
}

__device__ __forceinline__ void loadidx(
    int (&dst)[4], const int* __restrict__ nbr, int k, int n0, int ln)
{
    const int* nb = nbr + k * N_PTS;
#pragma unroll
    for (int mt = 0; mt < 4; mt++) {
        int nn = n0 + mt * 16 + ln;
        int v = (nn < N_PTS) ? nb[nn] : -1;
        dst[mt] = (v < 0) ? ZROW : v;
    }
}

template <int CIN>
__device__ __forceinline__ void conv_path(
    const f16* __restrict__ src, const f16* WtL,   // WtL points into LDS
    const int* __restrict__ nbr,
    int lane, int n0,
    const float* __restrict__ bns, const float* __restrict__ bnb,
    f16* __restrict__ msf, int colBase, float* __restrict__ pooled)
{
    constexpr int KS = CIN / 32;
    int ln = lane & 15, q = lane >> 4;

    f32x4 acc[4][4];
    for (int mt = 0; mt < 4; mt++) for (int nt = 0; nt < 4; nt++)
        acc[mt][nt] = (f32x4){0.f, 0.f, 0.f, 0.f};

    int  idxr[4][4];      // idx ring, distance 4
    uint4 raw[4][4][KS];  // row ring, depth 3

#pragma unroll
    for (int k = 0; k < 4; k++) loadidx(idxr[k], nbr, k, n0, ln);
#pragma unroll
    for (int k = 0; k < 3; k++) loadrows<CIN>(raw[k], idxr[k], src, q);
    __builtin_amdgcn_sched_barrier(0);

#pragma unroll
    for (int k = 0; k < 9; k++) {
        if (k + 3 < 9) loadrows<CIN>(raw[(k + 3) & 3], idxr[(k + 3) & 3], src, q);
        if (k + 4 < 9) loadidx(idxr[k & 3], nbr, k + 4, n0, ln);  // slot (k+4)&3 == k&3
        __builtin_amdgcn_sched_barrier(0);   // loads must be ISSUED before MFMAs
        const f16* Wk = WtL + k * (KS * 4 * 512);
        __builtin_amdgcn_s_setprio(1);
#pragma unroll
        for (int ks = 0; ks < KS; ks++)
#pragma unroll
            for (int nt = 0; nt < 4; nt++) {
                f16x8 b = *(const f16x8*)(Wk + (ks * 4 + nt) * 512 + lane * 8);
#pragma unroll
                for (int mt = 0; mt < 4; mt++) {
                    u4f16 v; v.u = raw[k & 3][mt][ks];
                    acc[mt][nt] = __builtin_amdgcn_mfma_f32_16x16x32_f16(v.h, b, acc[mt][nt], 0, 0, 0);
                }
            }
        __builtin_amdgcn_s_setprio(0);
    }

    // epilogue: BN + ReLU, store ms fp16, channel max -> pooled
#pragma unroll
    for (int nt = 0; nt < 4; nt++) {
        int ch = colBase + nt * 16 + ln;
        float s = bns[nt * 16 + ln], bb = bnb[nt * 16 + ln];
        float cmax = 0.f;
#pragma unroll
        for (int mt = 0; mt < 4; mt++)
#pragma unroll
            for (int r = 0; r < 4; r++) {
                int n = n0 + mt * 16 + q * 4 + r;   // always < NPAD
                float v = fmaxf(acc[mt][nt][r] * s + bb, 0.f);
                msf[(long)n * 192 + ch] = f2h(v);
                if (n < N_PTS) cmax = fmaxf(cmax, v);
            }
        cmax = fmaxf(cmax, __shfl_xor(cmax, 16));
        cmax = fmaxf(cmax, __shfl_xor(cmax, 32));
        if (q == 0) atomicMax((int*)(pooled + ch), __float_as_int(cmax));
    }
}

// One path per block; 8 waves (512 threads) handle 8 consecutive 64-pt tiles
// and share one LDS-staged weight set (72 KB max -> 2 blocks/CU, 16 waves/CU).
__global__ __launch_bounds__(512, 2) void k_conv(
    const f16* __restrict__ featf, const f16* __restrict__ hf,
    const f16* __restrict__ Wt1, const f16* __restrict__ Wt2b, const f16* __restrict__ Wt3,
    const int* __restrict__ nbr1, const int* __restrict__ nbr2,
    const float* __restrict__ bn1_s, const float* __restrict__ bn1_b,
    const float* __restrict__ bn2b_s, const float* __restrict__ bn2b_b,
    const float* __restrict__ bn3_s, const float* __restrict__ bn3_b,
    f16* __restrict__ msf, float* __restrict__ pooled, int g0)
{
    __shared__ f16 smem[9 * 64 * 64];   // 73728 B

    int path = blockIdx.x % 3;
    int g    = g0 + blockIdx.x / 3;
    int lane = threadIdx.x & 63, wave = threadIdx.x >> 6;
    int n0 = (g * 8 + wave) * 64;

    const f16* Wsrc = (path == 0) ? Wt1 : (path == 1) ? Wt2b : Wt3;
    int nchunk = (path == 1) ? (9 * 32 * 64 / 8) : (9 * 64 * 64 / 8);
    for (int i = threadIdx.x; i < nchunk; i += 512)
        ((uint4*)smem)[i] = ((const uint4*)Wsrc)[i];
    __syncthreads();

    if (path == 0)
        conv_path<64>(featf, smem, nbr1, lane, n0, bn1_s,  bn1_b,  msf, 0,   pooled);
    else if (path == 1)
        conv_path<32>(hf,    smem, nbr1, lane, n0, bn2b_s, bn2b_b, msf, 64,  pooled);
    else
        conv_path<64>(featf, smem, nbr2, lane, n0, bn3_s,  bn3_b,  msf, 128, pooled);
}

// ---------------------------------------------------------------------------
// fusion (attention folded in): 512-thread blocks (1172 total) to halve the
// redundant per-block attention-MLP/sWf prologues. Each block recomputes the
// tiny MLP from pooled, builds Wfst = attn*Wf fragment-linear in LDS, then
// out = relu(bnf( ms @ Wfst )) fp32 for 256 pts (8 waves x 32).
// msf loads TEMPORAL (L3-resident after conv); out stores nontemporal.
// ---------------------------------------------------------------------------
__global__ __launch_bounds__(512, 4) void k_fuse(
    const f16* __restrict__ msf, const float* __restrict__ pooled,
    const float* __restrict__ A1w, const float* __restrict__ A1b,
    const float* __restrict__ A2w, const float* __restrict__ A2b,
    const float* __restrict__ Wf,
    const float* __restrict__ sf, const float* __restrict__ bf_,
    float* __restrict__ out)
{
    __shared__ float sp[192], sa1[16], sattn[192];
    __shared__ f16 sWf[12288];
    int t = threadIdx.x;
    if (t < 192) sp[t] = pooled[t];
    __syncthreads();
    if (t < 16) {
        float a = A1b[t];
        for (int i = 0; i < 192; i++) a += sp[i] * A1w[i * 16 + t];
        sa1[t] = fmaxf(a, 0.f);
    }
    __syncthreads();
    if (t < 192) {
        float a = A2b[t];
        for (int i = 0; i < 16; i++) a += sa1[i] * A2w[i * 192 + t];
        sattn[t] = 1.f / (1.f + expf(-a));
    }
    __syncthreads();
    for (int i = t; i < 12288; i += 512) {   // 6*4*64*8 fragment-linear
        int j = i & 7, lane = (i >> 3) & 63, nt = (i >> 9) & 3, kt = i >> 11;
        int jrow = kt * 32 + (lane >> 4) * 8 + j, c = nt * 16 + (lane & 15);
        sWf[i] = f2h(Wf[jrow * 64 + c] * sattn[jrow]);
    }
    __syncthreads();

    int lane = threadIdx.x & 63, wave = threadIdx.x >> 6;
    int n0 = blockIdx.x * 256 + wave * 32;
    int ln = lane & 15, q = lane >> 4;

    uint4 araw[6][2];
#pragma unroll
    for (int kt = 0; kt < 6; kt++)
#pragma unroll
        for (int mt = 0; mt < 2; mt++)
            araw[kt][mt] = *(const uint4*)(msf + (long)(n0 + mt * 16 + ln) * 192 + kt * 32 + q * 8);

    f32x4 acc[2][4];
    for (int mt = 0; mt < 2; mt++) for (int nt = 0; nt < 4; nt++)
        acc[mt][nt] = (f32x4){0.f, 0.f, 0.f, 0.f};

#pragma unroll
    for (int kt = 0; kt < 6; kt++)
#pragma unroll
        for (int nt = 0; nt < 4; nt++) {
            f16x8 b = *(const f16x8*)(sWf + ((kt * 4 + nt) * 64 + lane) * 8);
#pragma unroll
            for (int mt = 0; mt < 2; mt++) {
                u4f16 v; v.u = araw[kt][mt];
                acc[mt][nt] = __builtin_amdgcn_mfma_f32_16x16x32_f16(v.h, b, acc[mt][nt], 0, 0, 0);
            }
        }

#pragma unroll
    for (int nt = 0; nt < 4; nt++) {
        int ch = nt * 16 + ln;
        float s = sf[ch], bb = bf_[ch];
#pragma unroll
        for (int mt = 0; mt < 2; mt++)
#pragma unroll
            for (int r = 0; r < 4; r++) {
                int n = n0 + mt * 16 + q * 4 + r;
                if (n < N_PTS)
                    __builtin_nontemporal_store(fmaxf(acc[mt][nt][r] * s + bb, 0.f),
                                                &out[(long)n * 64 + ch]);
            }
    }
}

// ---------------------------------------------------------------------------
extern "C" void kernel_launch(void* const* d_in, const int* in_sizes, int n_in,
                              void* d_out, int out_size, void* d_ws, size_t ws_size,
                              hipStream_t stream)
{
    const float* features = (const float*)d_in[0];
    const float* W1     = (const float*)d_in[1];
    const float* bn1_s  = (const float*)d_in[2];
    const float* bn1_b  = (const float*)d_in[3];
    const float* W2a    = (const float*)d_in[4];
    const float* bn2a_s = (const float*)d_in[5];
    const float* bn2a_b = (const float*)d_in[6];
    const float* W2b    = (const float*)d_in[7];
    const float* bn2b_s = (const float*)d_in[8];
    const float* bn2b_b = (const float*)d_in[9];
    const float* W3     = (const float*)d_in[10];
    const float* bn3_s  = (const float*)d_in[11];
    const float* bn3_b  = (const float*)d_in[12];
    const float* A1w    = (const float*)d_in[13];
    const float* A1b    = (const float*)d_in[14];
    const float* A2w    = (const float*)d_in[15];
    const float* A2b    = (const float*)d_in[16];
    const float* Wf     = (const float*)d_in[17];
    const float* bnf_s  = (const float*)d_in[18];
    const float* bnf_b  = (const float*)d_in[19];
    const int*   nbr1   = (const int*)d_in[20];
    const int*   nbr2   = (const int*)d_in[21];

    char* ws = (char*)d_ws;
    size_t off = 0;
    f16* featf = (f16*)(ws + off); off += (size_t)NPAD * 64 * 2;
    f16* hf    = (f16*)(ws + off); off += (size_t)NPAD * 32 * 2;
    f16* msf   = (f16*)(ws + off); off += (size_t)NPAD * 192 * 2;
    f16* Wt1   = (f16*)(ws + off); off += 9 * 64 * 64 * 2;
    f16* Wt3   = (f16*)(ws + off); off += 9 * 64 * 64 * 2;
    f16* Wt2b  = (f16*)(ws + off); off += 9 * 32 * 64 * 2;
    float* pooled = (float*)(ws + off); off += 256 * 4;

    k_head<<<HEAD_BLOCKS + WP_BLOCKS, 256, 0, stream>>>(
        features, W2a, bn2a_s, bn2a_b, W1, W2b, W3,
        featf, hf, Wt1, Wt2b, Wt3, pooled);

    // 586 tile-groups * 3 paths, split into two halves of 879 blocks each
    k_conv<<<293 * 3, 512, 0, stream>>>(featf, hf, Wt1, Wt2b, Wt3, nbr1, nbr2,
                                        bn1_s, bn1_b, bn2b_s, bn2b_b, bn3_s, bn3_b,
                                        msf, pooled, 0);
    k_conv<<<293 * 3, 512, 0, stream>>>(featf, hf, Wt1, Wt2b, Wt3, nbr1, nbr2,
                                        bn1_s, bn1_b, bn2b_s, bn2b_b, bn3_s, bn3_b,
                                        msf, pooled, 293);

    k_fuse<<<NPAD / 256, 512, 0, stream>>>(msf, pooled, A1w, A1b, A2w, A2b, Wf,
                                           bnf_s, bnf_b, (float*)d_out);
}

// Round 12
// 409.278 us; speedup vs baseline: 2.3898x; 1.0719x over previous
//
#include <hip/hip_runtime.h>

#define N_PTS 300000
#define NPAD  300032   // multiple of 256
#define ZROW  N_PTS    // zeroed feature row used for missing neighbors

typedef _Float16 f16;
typedef _Float16 f16x8 __attribute__((ext_vector_type(8)));
typedef float    f32x4 __attribute__((ext_vector_type(4)));

__device__ __forceinline__ f16 f2h(float x) { return (f16)x; }

union u4f16 { uint4 u; f16x8 h; };

#define HEAD_BLOCKS (NPAD / 256)   // 1172
#define WP_BLOCKS   361            // 361*256 covers 92160 weights + 192 pooled-init

// Fragment-linear weight layouts (so MFMA B-operands are lane-consecutive):
//   Wt1 / Wt3 : idx = (((k*2+ks)*4+nt)*64 + lane)*8 + j
//               value = W[k][d=ks*32+q*8+j][c=nt*16+ln]   (q=lane>>4, ln=lane&15)
//   Wt2b      : idx = ((k*4+nt)*64 + lane)*8 + j
//               value = W2b[k][d=q*8+j][c=nt*16+ln]

// ---------------------------------------------------------------------------
// head: fused feature-prep + bottleneck + weight repack + pooled zero-init.
// W2a B-fragments built ONCE per block in LDS (4 KB) instead of 128 scalar
// global loads + converts per thread.
// ---------------------------------------------------------------------------
__global__ __launch_bounds__(256) void k_head(
    const float* __restrict__ feat, const float* __restrict__ W2a,
    const float* __restrict__ s2a, const float* __restrict__ b2a,
    const float* __restrict__ W1, const float* __restrict__ W2b,
    const float* __restrict__ W3,
    f16* __restrict__ featf, f16* __restrict__ hf,
    f16* __restrict__ Wt1, f16* __restrict__ Wt2b, f16* __restrict__ Wt3,
    float* __restrict__ pooled)
{
    __shared__ f16 sWa[2048];   // W2a fragment-linear: [(ks*2+nt)*64+lane]*8+j

    if (blockIdx.x >= HEAD_BLOCKS) {   // weight-repack blocks
        int i = (blockIdx.x - HEAD_BLOCKS) * 256 + threadIdx.x;
        if (i < 36864) {                       // Wt1
            int j = i & 7, lane = (i >> 3) & 63, nt = (i >> 9) & 3,
                ks = (i >> 11) & 1, k = i >> 12;
            int d = ks * 32 + (lane >> 4) * 8 + j, c = nt * 16 + (lane & 15);
            Wt1[i] = f2h(W1[(k << 12) + (d << 6) + c]);
        } else if (i < 73728) {                // Wt3
            int ii = i - 36864;
            int j = ii & 7, lane = (ii >> 3) & 63, nt = (ii >> 9) & 3,
                ks = (ii >> 11) & 1, k = ii >> 12;
            int d = ks * 32 + (lane >> 4) * 8 + j, c = nt * 16 + (lane & 15);
            Wt3[ii] = f2h(W3[(k << 12) + (d << 6) + c]);
        } else if (i < 92160) {                // Wt2b
            int ii = i - 73728;
            int j = ii & 7, lane = (ii >> 3) & 63, nt = (ii >> 9) & 3, k = ii >> 11;
            int d = (lane >> 4) * 8 + j, c = nt * 16 + (lane & 15);
            Wt2b[ii] = f2h(W2b[k * 2048 + (d << 6) + c]);
        } else if (i < 92352) {                // pooled zero-init (replaces memset)
            pooled[i - 92160] = 0.f;
        }
        return;
    }

    // cooperative W2a fragment build: thread t -> (ks,nt,lane), 8 elements
    {
        int t = threadIdx.x;
        int lane_ = t & 63, nt_ = (t >> 6) & 1, ks_ = (t >> 7) & 1;
        int ln_ = lane_ & 15, q_ = lane_ >> 4;
#pragma unroll
        for (int j = 0; j < 8; j++)
            sWa[((ks_ * 2 + nt_) * 64 + lane_) * 8 + j] =
                f2h(W2a[(ks_ * 32 + q_ * 8 + j) * 32 + nt_ * 16 + ln_]);
    }
    __syncthreads();

    int lane = threadIdx.x & 63, wave = threadIdx.x >> 6;
    int n0 = (blockIdx.x * 4 + wave) * 64;
    int ln = lane & 15, q = lane >> 4;

    f16x8 a[4][2];
#pragma unroll
    for (int mt = 0; mt < 4; mt++) {
        int n = n0 + mt * 16 + ln;
#pragma unroll
        for (int ks = 0; ks < 2; ks++) {
            u4f16 v;
            if (n < N_PTS) {
                const float* p = feat + (long)n * 64 + ks * 32 + q * 8;
                float4 lo = *(const float4*)p;
                float4 hi = *(const float4*)(p + 4);
                v.h[0] = f2h(lo.x); v.h[1] = f2h(lo.y);
                v.h[2] = f2h(lo.z); v.h[3] = f2h(lo.w);
                v.h[4] = f2h(hi.x); v.h[5] = f2h(hi.y);
                v.h[6] = f2h(hi.z); v.h[7] = f2h(hi.w);
            } else {
                v.u = make_uint4(0u, 0u, 0u, 0u);
            }
            a[mt][ks] = v.h;
            *(uint4*)(featf + (long)n * 64 + ks * 32 + q * 8) = v.u;
        }
    }

    f32x4 acc[4][2];
    for (int mt = 0; mt < 4; mt++) for (int nt = 0; nt < 2; nt++)
        acc[mt][nt] = (f32x4){0.f, 0.f, 0.f, 0.f};
#pragma unroll
    for (int ks = 0; ks < 2; ks++)
#pragma unroll
        for (int nt = 0; nt < 2; nt++) {
            f16x8 b = *(const f16x8*)(sWa + ((ks * 2 + nt) * 64 + lane) * 8);
#pragma unroll
            for (int mt = 0; mt < 4; mt++)
                acc[mt][nt] = __builtin_amdgcn_mfma_f32_16x16x32_f16(a[mt][ks], b, acc[mt][nt], 0, 0, 0);
        }

#pragma unroll
    for (int nt = 0; nt < 2; nt++) {
        int ch = nt * 16 + ln;
        float s = s2a[ch], bb = b2a[ch];
#pragma unroll
        for (int mt = 0; mt < 4; mt++)
#pragma unroll
            for (int r = 0; r < 4; r++) {
                int n = n0 + mt * 16 + q * 4 + r;
                float v = (n < N_PTS) ? fmaxf(acc[mt][nt][r] * s + bb, 0.f) : 0.f;
                hf[(long)n * 32 + ch] = f2h(v);
            }
    }
}

// ---------------------------------------------------------------------------
// sparse-conv path: 64 pts/wave, rotating gather ring, ZROW remap.
// B operands come from LDS (fragment-linear) so they never touch vmcnt.
// 8 waves per block share one staged weight set (72 KB -> 2 blocks/CU).
// Paths interleaved per block (blockIdx%3): cross-path L2 reuse + good
// grid quantization. (Verified 174 µs configuration.)
// ---------------------------------------------------------------------------
template <int CIN>
__device__ __forceinline__ void loadrows(
    uint4 (&dst)[4][CIN / 32], const int (&idx)[4],
    const f16* __restrict__ src, int q)
{
#pragma unroll
    for (int mt = 0; mt < 4; mt++) {
        const f16* p = src + (long)idx[mt] * CIN + q * 8;
#pragma unroll
        for (int ks = 0; ks < CIN / 32; ks++)
            dst[mt][ks] = *(const uint4*)(p + ks * 32);
    }
}

__device__ __forceinline__ void loadidx(
    int (&dst)[4], const int* __restrict__ nbr, int k, int n0, int ln)
{
    const int* nb = nbr + k * N_PTS;
#pragma unroll
    for (int mt = 0; mt < 4; mt++) {
        int nn = n0 + mt * 16 + ln;
        int v = (nn < N_PTS) ? nb[nn] : -1;
        dst[mt] = (v < 0) ? ZROW : v;
    }
}

template <int CIN>
__device__ __forceinline__ void conv_path(
    const f16* __restrict__ src, const f16* WtL,   // WtL points into LDS
    const int* __restrict__ nbr,
    int lane, int n0,
    const float* __restrict__ bns, const float* __restrict__ bnb,
    f16* __restrict__ msf, int colBase, float* __restrict__ pooled)
{
    constexpr int KS = CIN / 32;
    int ln = lane & 15, q = lane >> 4;

    f32x4 acc[4][4];
    for (int mt = 0; mt < 4; mt++) for (int nt = 0; nt < 4; nt++)
        acc[mt][nt] = (f32x4){0.f, 0.f, 0.f, 0.f};

    int  idxr[4][4];      // idx ring, distance 4
    uint4 raw[4][4][KS];  // row ring, depth 3

#pragma unroll
    for (int k = 0; k < 4; k++) loadidx(idxr[k], nbr, k, n0, ln);
#pragma unroll
    for (int k = 0; k < 3; k++) loadrows<CIN>(raw[k], idxr[k], src, q);
    __builtin_amdgcn_sched_barrier(0);

#pragma unroll
    for (int k = 0; k < 9; k++) {
        if (k + 3 < 9) loadrows<CIN>(raw[(k + 3) & 3], idxr[(k + 3) & 3], src, q);
        if (k + 4 < 9) loadidx(idxr[k & 3], nbr, k + 4, n0, ln);  // slot (k+4)&3 == k&3
        __builtin_amdgcn_sched_barrier(0);   // loads must be ISSUED before MFMAs
        const f16* Wk = WtL + k * (KS * 4 * 512);
        __builtin_amdgcn_s_setprio(1);
#pragma unroll
        for (int ks = 0; ks < KS; ks++)
#pragma unroll
            for (int nt = 0; nt < 4; nt++) {
                f16x8 b = *(const f16x8*)(Wk + (ks * 4 + nt) * 512 + lane * 8);
#pragma unroll
                for (int mt = 0; mt < 4; mt++) {
                    u4f16 v; v.u = raw[k & 3][mt][ks];
                    acc[mt][nt] = __builtin_amdgcn_mfma_f32_16x16x32_f16(v.h, b, acc[mt][nt], 0, 0, 0);
                }
            }
        __builtin_amdgcn_s_setprio(0);
    }

    // epilogue: BN + ReLU, store ms fp16, channel max -> pooled
#pragma unroll
    for (int nt = 0; nt < 4; nt++) {
        int ch = colBase + nt * 16 + ln;
        float s = bns[nt * 16 + ln], bb = bnb[nt * 16 + ln];
        float cmax = 0.f;
#pragma unroll
        for (int mt = 0; mt < 4; mt++)
#pragma unroll
            for (int r = 0; r < 4; r++) {
                int n = n0 + mt * 16 + q * 4 + r;   // always < NPAD
                float v = fmaxf(acc[mt][nt][r] * s + bb, 0.f);
                msf[(long)n * 192 + ch] = f2h(v);
                if (n < N_PTS) cmax = fmaxf(cmax, v);
            }
        cmax = fmaxf(cmax, __shfl_xor(cmax, 16));
        cmax = fmaxf(cmax, __shfl_xor(cmax, 32));
        if (q == 0) atomicMax((int*)(pooled + ch), __float_as_int(cmax));
    }
}

// One path per block; 8 waves (512 threads) handle 8 consecutive 64-pt tiles
// and share one LDS-staged weight set (72 KB max -> 2 blocks/CU, 16 waves/CU).
__global__ __launch_bounds__(512, 2) void k_conv(
    const f16* __restrict__ featf, const f16* __restrict__ hf,
    const f16* __restrict__ Wt1, const f16* __restrict__ Wt2b, const f16* __restrict__ Wt3,
    const int* __restrict__ nbr1, const int* __restrict__ nbr2,
    const float* __restrict__ bn1_s, const float* __restrict__ bn1_b,
    const float* __restrict__ bn2b_s, const float* __restrict__ bn2b_b,
    const float* __restrict__ bn3_s, const float* __restrict__ bn3_b,
    f16* __restrict__ msf, float* __restrict__ pooled)
{
    __shared__ f16 smem[9 * 64 * 64];   // 73728 B

    int path = blockIdx.x % 3;
    int g    = blockIdx.x / 3;
    int lane = threadIdx.x & 63, wave = threadIdx.x >> 6;
    int n0 = (g * 8 + wave) * 64;

    const f16* Wsrc = (path == 0) ? Wt1 : (path == 1) ? Wt2b : Wt3;
    int nchunk = (path == 1) ? (9 * 32 * 64 / 8) : (9 * 64 * 64 / 8);
    for (int i = threadIdx.x; i < nchunk; i += 512)
        ((uint4*)smem)[i] = ((const uint4*)Wsrc)[i];
    __syncthreads();

    if (path == 0)
        conv_path<64>(featf, smem, nbr1, lane, n0, bn1_s,  bn1_b,  msf, 0,   pooled);
    else if (path == 1)
        conv_path<32>(hf,    smem, nbr1, lane, n0, bn2b_s, bn2b_b, msf, 64,  pooled);
    else
        conv_path<64>(featf, smem, nbr2, lane, n0, bn3_s,  bn3_b,  msf, 128, pooled);
}

// ---------------------------------------------------------------------------
// fusion (attention folded in): 512-thread blocks (1172 total). Each block
// recomputes the tiny MLP from pooled, builds Wfst = attn*Wf fragment-linear
// in LDS, then out = relu(bnf( ms @ Wfst )) fp32 for 256 pts (8 waves x 32).
// msf loads TEMPORAL (L3-resident after conv); out stores nontemporal.
// ---------------------------------------------------------------------------
__global__ __launch_bounds__(512, 4) void k_fuse(
    const f16* __restrict__ msf, const float* __restrict__ pooled,
    const float* __restrict__ A1w, const float* __restrict__ A1b,
    const float* __restrict__ A2w, const float* __restrict__ A2b,
    const float* __restrict__ Wf,
    const float* __restrict__ sf, const float* __restrict__ bf_,
    float* __restrict__ out)
{
    __shared__ float sp[192], sa1[16], sattn[192];
    __shared__ f16 sWf[12288];
    int t = threadIdx.x;
    if (t < 192) sp[t] = pooled[t];
    __syncthreads();
    if (t < 16) {
        float a = A1b[t];
        for (int i = 0; i < 192; i++) a += sp[i] * A1w[i * 16 + t];
        sa1[t] = fmaxf(a, 0.f);
    }
    __syncthreads();
    if (t < 192) {
        float a = A2b[t];
        for (int i = 0; i < 16; i++) a += sa1[i] * A2w[i * 192 + t];
        sattn[t] = 1.f / (1.f + expf(-a));
    }
    __syncthreads();
    for (int i = t; i < 12288; i += 512) {   // 6*4*64*8 fragment-linear
        int j = i & 7, lane = (i >> 3) & 63, nt = (i >> 9) & 3, kt = i >> 11;
        int jrow = kt * 32 + (lane >> 4) * 8 + j, c = nt * 16 + (lane & 15);
        sWf[i] = f2h(Wf[jrow * 64 + c] * sattn[jrow]);
    }
    __syncthreads();

    int lane = threadIdx.x & 63, wave = threadIdx.x >> 6;
    int n0 = blockIdx.x * 256 + wave * 32;
    int ln = lane & 15, q = lane >> 4;

    uint4 araw[6][2];
#pragma unroll
    for (int kt = 0; kt < 6; kt++)
#pragma unroll
        for (int mt = 0; mt < 2; mt++)
            araw[kt][mt] = *(const uint4*)(msf + (long)(n0 + mt * 16 + ln) * 192 + kt * 32 + q * 8);

    f32x4 acc[2][4];
    for (int mt = 0; mt < 2; mt++) for (int nt = 0; nt < 4; nt++)
        acc[mt][nt] = (f32x4){0.f, 0.f, 0.f, 0.f};

#pragma unroll
    for (int kt = 0; kt < 6; kt++)
#pragma unroll
        for (int nt = 0; nt < 4; nt++) {
            f16x8 b = *(const f16x8*)(sWf + ((kt * 4 + nt) * 64 + lane) * 8);
#pragma unroll
            for (int mt = 0; mt < 2; mt++) {
                u4f16 v; v.u = araw[kt][mt];
                acc[mt][nt] = __builtin_amdgcn_mfma_f32_16x16x32_f16(v.h, b, acc[mt][nt], 0, 0, 0);
            }
        }

#pragma unroll
    for (int nt = 0; nt < 4; nt++) {
        int ch = nt * 16 + ln;
        float s = sf[ch], bb = bf_[ch];
#pragma unroll
        for (int mt = 0; mt < 2; mt++)
#pragma unroll
            for (int r = 0; r < 4; r++) {
                int n = n0 + mt * 16 + q * 4 + r;
                if (n < N_PTS)
                    __builtin_nontemporal_store(fmaxf(acc[mt][nt][r] * s + bb, 0.f),
                                                &out[(long)n * 64 + ch]);
            }
    }
}

// ---------------------------------------------------------------------------
extern "C" void kernel_launch(void* const* d_in, const int* in_sizes, int n_in,
                              void* d_out, int out_size, void* d_ws, size_t ws_size,
                              hipStream_t stream)
{
    const float* features = (const float*)d_in[0];
    const float* W1     = (const float*)d_in[1];
    const float* bn1_s  = (const float*)d_in[2];
    const float* bn1_b  = (const float*)d_in[3];
    const float* W2a    = (const float*)d_in[4];
    const float* bn2a_s = (const float*)d_in[5];
    const float* bn2a_b = (const float*)d_in[6];
    const float* W2b    = (const float*)d_in[7];
    const float* bn2b_s = (const float*)d_in[8];
    const float* bn2b_b = (const float*)d_in[9];
    const float* W3     = (const float*)d_in[10];
    const float* bn3_s  = (const float*)d_in[11];
    const float* bn3_b  = (const float*)d_in[12];
    const float* A1w    = (const float*)d_in[13];
    const float* A1b    = (const float*)d_in[14];
    const float* A2w    = (const float*)d_in[15];
    const float* A2b    = (const float*)d_in[16];
    const float* Wf     = (const float*)d_in[17];
    const float* bnf_s  = (const float*)d_in[18];
    const float* bnf_b  = (const float*)d_in[19];
    const int*   nbr1   = (const int*)d_in[20];
    const int*   nbr2   = (const int*)d_in[21];

    char* ws = (char*)d_ws;
    size_t off = 0;
    f16* featf = (f16*)(ws + off); off += (size_t)NPAD * 64 * 2;
    f16* hf    = (f16*)(ws + off); off += (size_t)NPAD * 32 * 2;
    f16* msf   = (f16*)(ws + off); off += (size_t)NPAD * 192 * 2;
    f16* Wt1   = (f16*)(ws + off); off += 9 * 64 * 64 * 2;
    f16* Wt3   = (f16*)(ws + off); off += 9 * 64 * 64 * 2;
    f16* Wt2b  = (f16*)(ws + off); off += 9 * 32 * 64 * 2;
    float* pooled = (float*)(ws + off); off += 256 * 4;

    k_head<<<HEAD_BLOCKS + WP_BLOCKS, 256, 0, stream>>>(
        features, W2a, bn2a_s, bn2a_b, W1, W2b, W3,
        featf, hf, Wt1, Wt2b, Wt3, pooled);

    // 586 tile-groups * 3 paths, one path per 8-wave block (verified 174 µs)
    k_conv<<<(NPAD / 64 / 8) * 3, 512, 0, stream>>>(featf, hf, Wt1, Wt2b, Wt3, nbr1, nbr2,
                                           bn1_s, bn1_b, bn2b_s, bn2b_b, bn3_s, bn3_b,
                                           msf, pooled);

    k_fuse<<<NPAD / 256, 512, 0, stream>>>(msf, pooled, A1w, A1b, A2w, A2b, Wf,
                                           bnf_s, bnf_b, (float*)d_out);
}

// Round 13
// 407.405 us; speedup vs baseline: 2.4008x; 1.0046x over previous
//
#include <hip/hip_runtime.h>

#define N_PTS 300000
#define NPAD  300032   // multiple of 256
#define ZROW  N_PTS    // zeroed feature row used for missing neighbors

typedef _Float16 f16;
typedef _Float16 f16x8 __attribute__((ext_vector_type(8)));
typedef float    f32x4 __attribute__((ext_vector_type(4)));

__device__ __forceinline__ f16 f2h(float x) { return (f16)x; }

union u4f16 { uint4 u; f16x8 h; };

#define HEAD_BLOCKS (NPAD / 256)   // 1172
#define WP_BLOCKS   361            // 361*256 covers 92160 weights + 192 pooled-init

// Fragment-linear weight layouts (so MFMA B-operands are lane-consecutive):
//   Wt1 / Wt3 : idx = (((k*2+ks)*4+nt)*64 + lane)*8 + j
//               value = W[k][d=ks*32+q*8+j][c=nt*16+ln]   (q=lane>>4, ln=lane&15)
//   Wt2b      : idx = ((k*4+nt)*64 + lane)*8 + j
//               value = W2b[k][d=q*8+j][c=nt*16+ln]

// ---------------------------------------------------------------------------
// head: fused feature-prep + bottleneck + weight repack + pooled zero-init.
// W2a B-fragments built ONCE per block in LDS (4 KB) instead of 128 scalar
// global loads + converts per thread.
// ---------------------------------------------------------------------------
__global__ __launch_bounds__(256) void k_head(
    const float* __restrict__ feat, const float* __restrict__ W2a,
    const float* __restrict__ s2a, const float* __restrict__ b2a,
    const float* __restrict__ W1, const float* __restrict__ W2b,
    const float* __restrict__ W3,
    f16* __restrict__ featf, f16* __restrict__ hf,
    f16* __restrict__ Wt1, f16* __restrict__ Wt2b, f16* __restrict__ Wt3,
    float* __restrict__ pooled)
{
    __shared__ f16 sWa[2048];   // W2a fragment-linear: [(ks*2+nt)*64+lane]*8+j

    if (blockIdx.x >= HEAD_BLOCKS) {   // weight-repack blocks
        int i = (blockIdx.x - HEAD_BLOCKS) * 256 + threadIdx.x;
        if (i < 36864) {                       // Wt1
            int j = i & 7, lane = (i >> 3) & 63, nt = (i >> 9) & 3,
                ks = (i >> 11) & 1, k = i >> 12;
            int d = ks * 32 + (lane >> 4) * 8 + j, c = nt * 16 + (lane & 15);
            Wt1[i] = f2h(W1[(k << 12) + (d << 6) + c]);
        } else if (i < 73728) {                // Wt3
            int ii = i - 36864;
            int j = ii & 7, lane = (ii >> 3) & 63, nt = (ii >> 9) & 3,
                ks = (ii >> 11) & 1, k = ii >> 12;
            int d = ks * 32 + (lane >> 4) * 8 + j, c = nt * 16 + (lane & 15);
            Wt3[ii] = f2h(W3[(k << 12) + (d << 6) + c]);
        } else if (i < 92160) {                // Wt2b
            int ii = i - 73728;
            int j = ii & 7, lane = (ii >> 3) & 63, nt = (ii >> 9) & 3, k = ii >> 11;
            int d = (lane >> 4) * 8 + j, c = nt * 16 + (lane & 15);
            Wt2b[ii] = f2h(W2b[k * 2048 + (d << 6) + c]);
        } else if (i < 92352) {                // pooled zero-init (replaces memset)
            pooled[i - 92160] = 0.f;
        }
        return;
    }

    // cooperative W2a fragment build: thread t -> (ks,nt,lane), 8 elements
    {
        int t = threadIdx.x;
        int lane_ = t & 63, nt_ = (t >> 6) & 1, ks_ = (t >> 7) & 1;
        int ln_ = lane_ & 15, q_ = lane_ >> 4;
#pragma unroll
        for (int j = 0; j < 8; j++)
            sWa[((ks_ * 2 + nt_) * 64 + lane_) * 8 + j] =
                f2h(W2a[(ks_ * 32 + q_ * 8 + j) * 32 + nt_ * 16 + ln_]);
    }
    __syncthreads();

    int lane = threadIdx.x & 63, wave = threadIdx.x >> 6;
    int n0 = (blockIdx.x * 4 + wave) * 64;
    int ln = lane & 15, q = lane >> 4;

    f16x8 a[4][2];
#pragma unroll
    for (int mt = 0; mt < 4; mt++) {
        int n = n0 + mt * 16 + ln;
#pragma unroll
        for (int ks = 0; ks < 2; ks++) {
            u4f16 v;
            if (n < N_PTS) {
                const float* p = feat + (long)n * 64 + ks * 32 + q * 8;
                float4 lo = *(const float4*)p;
                float4 hi = *(const float4*)(p + 4);
                v.h[0] = f2h(lo.x); v.h[1] = f2h(lo.y);
                v.h[2] = f2h(lo.z); v.h[3] = f2h(lo.w);
                v.h[4] = f2h(hi.x); v.h[5] = f2h(hi.y);
                v.h[6] = f2h(hi.z); v.h[7] = f2h(hi.w);
            } else {
                v.u = make_uint4(0u, 0u, 0u, 0u);
            }
            a[mt][ks] = v.h;
            *(uint4*)(featf + (long)n * 64 + ks * 32 + q * 8) = v.u;
        }
    }

    f32x4 acc[4][2];
    for (int mt = 0; mt < 4; mt++) for (int nt = 0; nt < 2; nt++)
        acc[mt][nt] = (f32x4){0.f, 0.f, 0.f, 0.f};
#pragma unroll
    for (int ks = 0; ks < 2; ks++)
#pragma unroll
        for (int nt = 0; nt < 2; nt++) {
            f16x8 b = *(const f16x8*)(sWa + ((ks * 2 + nt) * 64 + lane) * 8);
#pragma unroll
            for (int mt = 0; mt < 4; mt++)
                acc[mt][nt] = __builtin_amdgcn_mfma_f32_16x16x32_f16(a[mt][ks], b, acc[mt][nt], 0, 0, 0);
        }

#pragma unroll
    for (int nt = 0; nt < 2; nt++) {
        int ch = nt * 16 + ln;
        float s = s2a[ch], bb = b2a[ch];
#pragma unroll
        for (int mt = 0; mt < 4; mt++)
#pragma unroll
            for (int r = 0; r < 4; r++) {
                int n = n0 + mt * 16 + q * 4 + r;
                float v = (n < N_PTS) ? fmaxf(acc[mt][nt][r] * s + bb, 0.f) : 0.f;
                hf[(long)n * 32 + ch] = f2h(v);
            }
    }
}

// ---------------------------------------------------------------------------
// sparse-conv path: 64 pts/wave, rotating gather ring, ZROW remap.
// B operands come from LDS (fragment-linear) so they never touch vmcnt.
// 8 waves per block share one staged weight set (72 KB -> 2 blocks/CU).
// Paths interleaved per block (blockIdx%3): cross-path L2 reuse + good
// grid quantization. (Verified 174-176 µs configuration.)
// ---------------------------------------------------------------------------
template <int CIN>
__device__ __forceinline__ void loadrows(
    uint4 (&dst)[4][CIN / 32], const int (&idx)[4],
    const f16* __restrict__ src, int q)
{
#pragma unroll
    for (int mt = 0; mt < 4; mt++) {
        const f16* p = src + (long)idx[mt] * CIN + q * 8;
#pragma unroll
        for (int ks = 0; ks < CIN / 32; ks++)
            dst[mt][ks] = *(const uint4*)(p + ks * 32);
    }
}

__device__ __forceinline__ void loadidx(
    int (&dst)[4], const int* __restrict__ nbr, int k, int n0, int ln)
{
    const int* nb = nbr + k * N_PTS;
#pragma unroll
    for (int mt = 0; mt < 4; mt++) {
        int nn = n0 + mt * 16 + ln;
        int v = (nn < N_PTS) ? nb[nn] : -1;
        dst[mt] = (v < 0) ? ZROW : v;
    }
}

template <int CIN>
__device__ __forceinline__ void conv_path(
    const f16* __restrict__ src, const f16* WtL,   // WtL points into LDS
    const int* __restrict__ nbr,
    int lane, int n0,
    const float* __restrict__ bns, const float* __restrict__ bnb,
    f16* __restrict__ msf, int colBase, float* __restrict__ pooled)
{
    constexpr int KS = CIN / 32;
    int ln = lane & 15, q = lane >> 4;

    f32x4 acc[4][4];
    for (int mt = 0; mt < 4; mt++) for (int nt = 0; nt < 4; nt++)
        acc[mt][nt] = (f32x4){0.f, 0.f, 0.f, 0.f};

    int  idxr[4][4];      // idx ring, distance 4
    uint4 raw[4][4][KS];  // row ring, depth 3

#pragma unroll
    for (int k = 0; k < 4; k++) loadidx(idxr[k], nbr, k, n0, ln);
#pragma unroll
    for (int k = 0; k < 3; k++) loadrows<CIN>(raw[k], idxr[k], src, q);
    __builtin_amdgcn_sched_barrier(0);

#pragma unroll
    for (int k = 0; k < 9; k++) {
        if (k + 3 < 9) loadrows<CIN>(raw[(k + 3) & 3], idxr[(k + 3) & 3], src, q);
        if (k + 4 < 9) loadidx(idxr[k & 3], nbr, k + 4, n0, ln);  // slot (k+4)&3 == k&3
        __builtin_amdgcn_sched_barrier(0);   // loads must be ISSUED before MFMAs
        const f16* Wk = WtL + k * (KS * 4 * 512);
        __builtin_amdgcn_s_setprio(1);
#pragma unroll
        for (int ks = 0; ks < KS; ks++)
#pragma unroll
            for (int nt = 0; nt < 4; nt++) {
                f16x8 b = *(const f16x8*)(Wk + (ks * 4 + nt) * 512 + lane * 8);
#pragma unroll
                for (int mt = 0; mt < 4; mt++) {
                    u4f16 v; v.u = raw[k & 3][mt][ks];
                    acc[mt][nt] = __builtin_amdgcn_mfma_f32_16x16x32_f16(v.h, b, acc[mt][nt], 0, 0, 0);
                }
            }
        __builtin_amdgcn_s_setprio(0);
    }

    // epilogue: BN + ReLU, store ms fp16, channel max -> pooled
#pragma unroll
    for (int nt = 0; nt < 4; nt++) {
        int ch = colBase + nt * 16 + ln;
        float s = bns[nt * 16 + ln], bb = bnb[nt * 16 + ln];
        float cmax = 0.f;
#pragma unroll
        for (int mt = 0; mt < 4; mt++)
#pragma unroll
            for (int r = 0; r < 4; r++) {
                int n = n0 + mt * 16 + q * 4 + r;   // always < NPAD
                float v = fmaxf(acc[mt][nt][r] * s + bb, 0.f);
                msf[(long)n * 192 + ch] = f2h(v);
                if (n < N_PTS) cmax = fmaxf(cmax, v);
            }
        cmax = fmaxf(cmax, __shfl_xor(cmax, 16));
        cmax = fmaxf(cmax, __shfl_xor(cmax, 32));
        if (q == 0) atomicMax((int*)(pooled + ch), __float_as_int(cmax));
    }
}

// One path per block; 8 waves (512 threads) handle 8 consecutive 64-pt tiles
// and share one LDS-staged weight set (72 KB max -> 2 blocks/CU, 16 waves/CU).
__global__ __launch_bounds__(512, 2) void k_conv(
    const f16* __restrict__ featf, const f16* __restrict__ hf,
    const f16* __restrict__ Wt1, const f16* __restrict__ Wt2b, const f16* __restrict__ Wt3,
    const int* __restrict__ nbr1, const int* __restrict__ nbr2,
    const float* __restrict__ bn1_s, const float* __restrict__ bn1_b,
    const float* __restrict__ bn2b_s, const float* __restrict__ bn2b_b,
    const float* __restrict__ bn3_s, const float* __restrict__ bn3_b,
    f16* __restrict__ msf, float* __restrict__ pooled)
{
    __shared__ f16 smem[9 * 64 * 64];   // 73728 B

    int path = blockIdx.x % 3;
    int g    = blockIdx.x / 3;
    int lane = threadIdx.x & 63, wave = threadIdx.x >> 6;
    int n0 = (g * 8 + wave) * 64;

    const f16* Wsrc = (path == 0) ? Wt1 : (path == 1) ? Wt2b : Wt3;
    int nchunk = (path == 1) ? (9 * 32 * 64 / 8) : (9 * 64 * 64 / 8);
    for (int i = threadIdx.x; i < nchunk; i += 512)
        ((uint4*)smem)[i] = ((const uint4*)Wsrc)[i];
    __syncthreads();

    if (path == 0)
        conv_path<64>(featf, smem, nbr1, lane, n0, bn1_s,  bn1_b,  msf, 0,   pooled);
    else if (path == 1)
        conv_path<32>(hf,    smem, nbr1, lane, n0, bn2b_s, bn2b_b, msf, 64,  pooled);
    else
        conv_path<64>(featf, smem, nbr2, lane, n0, bn3_s,  bn3_b,  msf, 128, pooled);
}

// ---------------------------------------------------------------------------
// fusion (attention folded in): 512-thread blocks (1172 total). Each block
// recomputes the tiny MLP from pooled, builds Wfst = attn*Wf fragment-linear
// in LDS, then out = relu(bnf( ms @ Wfst )) fp32 for 256 pts (8 waves x 32).
// __launch_bounds__(512, 2): 128-VGPR budget -- the previous (512,4) forced
// a 64-VGPR cap and spilled araw/acc (~95 live regs) to scratch.
// msf loads TEMPORAL (L3-resident after conv); out stores nontemporal.
// ---------------------------------------------------------------------------
__global__ __launch_bounds__(512, 2) void k_fuse(
    const f16* __restrict__ msf, const float* __restrict__ pooled,
    const float* __restrict__ A1w, const float* __restrict__ A1b,
    const float* __restrict__ A2w, const float* __restrict__ A2b,
    const float* __restrict__ Wf,
    const float* __restrict__ sf, const float* __restrict__ bf_,
    float* __restrict__ out)
{
    __shared__ float sp[192], sa1[16], sattn[192];
    __shared__ f16 sWf[12288];
    int t = threadIdx.x;
    if (t < 192) sp[t] = pooled[t];
    __syncthreads();
    if (t < 16) {
        float a = A1b[t];
        for (int i = 0; i < 192; i++) a += sp[i] * A1w[i * 16 + t];
        sa1[t] = fmaxf(a, 0.f);
    }
    __syncthreads();
    if (t < 192) {
        float a = A2b[t];
        for (int i = 0; i < 16; i++) a += sa1[i] * A2w[i * 192 + t];
        sattn[t] = 1.f / (1.f + expf(-a));
    }
    __syncthreads();
    for (int i = t; i < 12288; i += 512) {   // 6*4*64*8 fragment-linear
        int j = i & 7, lane = (i >> 3) & 63, nt = (i >> 9) & 3, kt = i >> 11;
        int jrow = kt * 32 + (lane >> 4) * 8 + j, c = nt * 16 + (lane & 15);
        sWf[i] = f2h(Wf[jrow * 64 + c] * sattn[jrow]);
    }
    __syncthreads();

    int lane = threadIdx.x & 63, wave = threadIdx.x >> 6;
    int n0 = blockIdx.x * 256 + wave * 32;
    int ln = lane & 15, q = lane >> 4;

    uint4 araw[6][2];
#pragma unroll
    for (int kt = 0; kt < 6; kt++)
#pragma unroll
        for (int mt = 0; mt < 2; mt++)
            araw[kt][mt] = *(const uint4*)(msf + (long)(n0 + mt * 16 + ln) * 192 + kt * 32 + q * 8);

    f32x4 acc[2][4];
    for (int mt = 0; mt < 2; mt++) for (int nt = 0; nt < 4; nt++)
        acc[mt][nt] = (f32x4){0.f, 0.f, 0.f, 0.f};

#pragma unroll
    for (int kt = 0; kt < 6; kt++)
#pragma unroll
        for (int nt = 0; nt < 4; nt++) {
            f16x8 b = *(const f16x8*)(sWf + ((kt * 4 + nt) * 64 + lane) * 8);
#pragma unroll
            for (int mt = 0; mt < 2; mt++) {
                u4f16 v; v.u = araw[kt][mt];
                acc[mt][nt] = __builtin_amdgcn_mfma_f32_16x16x32_f16(v.h, b, acc[mt][nt], 0, 0, 0);
            }
        }

#pragma unroll
    for (int nt = 0; nt < 4; nt++) {
        int ch = nt * 16 + ln;
        float s = sf[ch], bb = bf_[ch];
#pragma unroll
        for (int mt = 0; mt < 2; mt++)
#pragma unroll
            for (int r = 0; r < 4; r++) {
                int n = n0 + mt * 16 + q * 4 + r;
                if (n < N_PTS)
                    __builtin_nontemporal_store(fmaxf(acc[mt][nt][r] * s + bb, 0.f),
                                                &out[(long)n * 64 + ch]);
            }
    }
}

// ---------------------------------------------------------------------------
extern "C" void kernel_launch(void* const* d_in, const int* in_sizes, int n_in,
                              void* d_out, int out_size, void* d_ws, size_t ws_size,
                              hipStream_t stream)
{
    const float* features = (const float*)d_in[0];
    const float* W1     = (const float*)d_in[1];
    const float* bn1_s  = (const float*)d_in[2];
    const float* bn1_b  = (const float*)d_in[3];
    const float* W2a    = (const float*)d_in[4];
    const float* bn2a_s = (const float*)d_in[5];
    const float* bn2a_b = (const float*)d_in[6];
    const float* W2b    = (const float*)d_in[7];
    const float* bn2b_s = (const float*)d_in[8];
    const float* bn2b_b = (const float*)d_in[9];
    const float* W3     = (const float*)d_in[10];
    const float* bn3_s  = (const float*)d_in[11];
    const float* bn3_b  = (const float*)d_in[12];
    const float* A1w    = (const float*)d_in[13];
    const float* A1b    = (const float*)d_in[14];
    const float* A2w    = (const float*)d_in[15];
    const float* A2b    = (const float*)d_in[16];
    const float* Wf     = (const float*)d_in[17];
    const float* bnf_s  = (const float*)d_in[18];
    const float* bnf_b  = (const float*)d_in[19];
    const int*   nbr1   = (const int*)d_in[20];
    const int*   nbr2   = (const int*)d_in[21];

    char* ws = (char*)d_ws;
    size_t off = 0;
    f16* featf = (f16*)(ws + off); off += (size_t)NPAD * 64 * 2;
    f16* hf    = (f16*)(ws + off); off += (size_t)NPAD * 32 * 2;
    f16* msf   = (f16*)(ws + off); off += (size_t)NPAD * 192 * 2;
    f16* Wt1   = (f16*)(ws + off); off += 9 * 64 * 64 * 2;
    f16* Wt3   = (f16*)(ws + off); off += 9 * 64 * 64 * 2;
    f16* Wt2b  = (f16*)(ws + off); off += 9 * 32 * 64 * 2;
    float* pooled = (float*)(ws + off); off += 256 * 4;

    k_head<<<HEAD_BLOCKS + WP_BLOCKS, 256, 0, stream>>>(
        features, W2a, bn2a_s, bn2a_b, W1, W2b, W3,
        featf, hf, Wt1, Wt2b, Wt3, pooled);

    // 586 tile-groups * 3 paths, one path per 8-wave block (verified 174 µs)
    k_conv<<<(NPAD / 64 / 8) * 3, 512, 0, stream>>>(featf, hf, Wt1, Wt2b, Wt3, nbr1, nbr2,
                                           bn1_s, bn1_b, bn2b_s, bn2b_b, bn3_s, bn3_b,
                                           msf, pooled);

    k_fuse<<<NPAD / 256, 512, 0, stream>>>(msf, pooled, A1w, A1b, A2w, A2b, Wf,
                                           bnf_s, bnf_b, (float*)d_out);
}